// Round 13
// baseline (230.367 us; speedup 1.0000x reference)
//
#include <hip/hip_runtime.h>
#include <hip/hip_bf16.h>

typedef __attribute__((ext_vector_type(8))) short s16x8;
typedef __attribute__((ext_vector_type(4))) float f32x4;
typedef __attribute__((ext_vector_type(16))) float f32x16;

__device__ inline float bf2f(unsigned short u) {
  union { unsigned int i; float f; } v; v.i = ((unsigned int)u) << 16; return v.f;
}
__device__ inline unsigned short f2bf(float f) {
  union { float f; unsigned int i; } v; v.f = f;
  unsigned int r = (v.i + 0x7FFFu + ((v.i >> 16) & 1u)) >> 16;
  return (unsigned short)r;
}
__device__ inline void gl_lds16(const void* g, void* l) {
  __builtin_amdgcn_global_load_lds(
      (const __attribute__((address_space(1))) unsigned int*)g,
      (__attribute__((address_space(3))) unsigned int*)l, 16, 0, 0);
}

// ---------------- elementwise cast x -> bf16 ----------------
__global__ __launch_bounds__(256) void cast_to_bf16(const float* __restrict__ s,
                                                    unsigned short* __restrict__ d, int n4) {
  int i = blockIdx.x * 256 + threadIdx.x;
  if (i >= n4) return;
  float4 v = ((const float4*)s)[i];
  ushort4 o;
  o.x = f2bf(v.x); o.y = f2bf(v.y); o.z = f2bf(v.z); o.w = f2bf(v.w);
  ((ushort4*)d)[i] = o;
}

// ---------------- transpose + cast weight: src[K][N] f32 -> dst[N][K] bf16 ----------------
__global__ __launch_bounds__(256) void transpose_cast(const float* __restrict__ src,
                                                      unsigned short* __restrict__ dst,
                                                      int K, int N) {
  __shared__ float tile[32][33];
  int n0 = blockIdx.x * 32, k0 = blockIdx.y * 32;
  int tx = threadIdx.x & 31, ty = threadIdx.x >> 5;
#pragma unroll
  for (int i = 0; i < 4; ++i) {
    int k = ty + i * 8;
    tile[k][tx] = src[(size_t)(k0 + k) * N + n0 + tx];
  }
  __syncthreads();
#pragma unroll
  for (int i = 0; i < 4; ++i) {
    int n = ty + i * 8;
    dst[(size_t)(n0 + n) * K + k0 + tx] = f2bf(tile[tx][n]);
  }
}

// ---------------- RoPE tables ----------------
__global__ __launch_bounds__(256) void rope_tables(float* __restrict__ ct, float* __restrict__ st) {
  int idx = blockIdx.x * 256 + threadIdx.x;  // 2048*64
  int s = idx >> 6, i = idx & 63;
  float inv = powf(10000.0f, -(float)(2 * i) * (1.0f / 128.0f));
  float ang = (float)s * inv;
  ct[idx] = cosf(ang);
  st[idx] = sinf(ang);
}

// ---------------- RoPE apply in place on Q (16 heads) and K (4 heads) ----------------
__global__ __launch_bounds__(256) void rope_apply(unsigned short* __restrict__ qkv,
                                                  const float* __restrict__ ct,
                                                  const float* __restrict__ st) {
  int row = blockIdx.x;  // 0..4095 = b*2048+s
  int pos = row & 2047;
  unsigned short* base = qkv + (size_t)row * 3072;
  for (int it = threadIdx.x; it < 1280; it += 256) {  // 20 heads * 64 half-dims
    int head = it >> 6, dh = it & 63;
    int col = head < 16 ? head * 128 : 2048 + (head - 16) * 128;
    float a = bf2f(base[col + dh]);
    float b = bf2f(base[col + dh + 64]);
    float c = ct[pos * 64 + dh], sn = st[pos * 64 + dh];
    base[col + dh] = f2bf(a * c - b * sn);
    base[col + dh + 64] = f2bf(b * c + a * sn);
  }
}

// ---------------- V transpose: qkv V cols -> vt[(b*4+kvh)*128 + d][s] ----------------
__global__ __launch_bounds__(256) void vtrans(const unsigned short* __restrict__ qkv,
                                              unsigned short* __restrict__ vt) {
  __shared__ unsigned short tile[32][33];
  int tx = threadIdx.x & 31, ty = threadIdx.x >> 5;
  int s0 = blockIdx.x * 32;
  int d0 = blockIdx.y * 32;
  int bz = blockIdx.z;  // b*4 + kvh
  const unsigned short* src = qkv + (size_t)((bz >> 2) * 2048) * 3072 + 2560 + (bz & 3) * 128;
#pragma unroll
  for (int i = 0; i < 4; ++i)
    tile[ty + i * 8][tx] = src[(size_t)(s0 + ty + i * 8) * 3072 + d0 + tx];
  __syncthreads();
  unsigned short* dst = vt + (size_t)bz * 128 * 2048;
#pragma unroll
  for (int i = 0; i < 4; ++i)
    dst[(size_t)(d0 + ty + i * 8) * 2048 + s0 + tx] = tile[tx][ty + i * 8];
}

// ---------------- 256x256 8-phase GEMM: C[M,N] = A[M,K] * BT[N,K]^T ----------------
template <int BF16OUT>
__global__ __launch_bounds__(512, 2) void gemm256(const unsigned short* __restrict__ A,
                                                  const unsigned short* __restrict__ BT,
                                                  void* __restrict__ Cv,
                                                  int M, int N, int K) {
  __shared__ __align__(16) unsigned short Lds[2][4][256 * 32];  // 128 KiB
  const int t = threadIdx.x, lane = t & 63;
  const int wid = t >> 6, m16 = lane & 15, l4 = lane >> 4;
  const int wm = wid >> 2, wn = wid & 3;
  const int swA = (l4 ^ ((m16 >> 1) & 3)) * 16;  // read-side swizzled 16B slot

  int gx = gridDim.x, nwg = gx * gridDim.y;
  int wg = blockIdx.y * gx + blockIdx.x;
  if ((nwg & 7) == 0) { int q = nwg >> 3; wg = (wg & 7) * q + (wg >> 3); }
  const int rowBase = (wg / gx) * 256, colBase = (wg % gx) * 256;

  const int r0 = t >> 2, c80 = (t & 3) ^ ((r0 >> 1) & 3);
  const int g1 = 512 + t, r1 = g1 >> 2, c81 = (g1 & 3) ^ ((r1 >> 1) & 3);
  const char* pA0 = (const char*)(A + (size_t)(rowBase + r0) * K + c80 * 8);
  const char* pA1 = (const char*)(A + (size_t)(rowBase + r1) * K + c81 * 8);
  const char* pB0 = (const char*)(BT + (size_t)(colBase + r0) * K + c80 * 8);
  const char* pB1 = (const char*)(BT + (size_t)(colBase + r1) * K + c81 * 8);

  f32x4 acc[8][4];
#pragma unroll
  for (int fr = 0; fr < 8; ++fr)
#pragma unroll
    for (int fn = 0; fn < 4; ++fn) {
      f32x4 z = {0.f, 0.f, 0.f, 0.f};
      acc[fr][fn] = z;
    }
  s16x8 bf[4];

#define STG(mat, kc, kt, buf)                                             \
  {                                                                       \
    size_t ko = (size_t)((kt) * 64 + (kc) * 32) * 2;                      \
    char* pl = (char*)&Lds[buf][(mat) * 2 + (kc)][0];                     \
    gl_lds16(((mat) ? pB0 : pA0) + ko, pl + t * 16);                      \
    gl_lds16(((mat) ? pB1 : pA1) + ko, pl + 8192 + t * 16);               \
  }

#define GATE()                                         \
  asm volatile("s_waitcnt vmcnt(8)" ::: "memory");     \
  __builtin_amdgcn_s_barrier();                        \
  __builtin_amdgcn_sched_barrier(0);

#define CMP(cur, kc, frh)                                                          \
  {                                                                                \
    const char* Ap = (const char*)&Lds[cur][kc][0];                                \
    s16x8 af[4];                                                                   \
    _Pragma("unroll") for (int i = 0; i < 4; ++i)                                  \
        af[i] = *(const s16x8*)(Ap + (wm * 128 + ((frh) * 4 + i) * 16 + m16) * 64 + swA); \
    if ((frh) == 0) {                                                              \
      const char* Bp = (const char*)&Lds[cur][2 + (kc)][0];                        \
      _Pragma("unroll") for (int n = 0; n < 4; ++n)                                \
          bf[n] = *(const s16x8*)(Bp + (wn * 64 + n * 16 + m16) * 64 + swA);       \
    }                                                                              \
    __builtin_amdgcn_s_setprio(1);                                                 \
    _Pragma("unroll") for (int i = 0; i < 4; ++i)                                  \
        _Pragma("unroll") for (int n = 0; n < 4; ++n)                              \
            acc[(frh) * 4 + i][n] = __builtin_amdgcn_mfma_f32_16x16x32_bf16(       \
                af[i], bf[n], acc[(frh) * 4 + i][n], 0, 0, 0);                     \
    __builtin_amdgcn_s_setprio(0);                                                 \
  }

  const int NT = K >> 6;
  STG(0, 0, 0, 0); STG(1, 0, 0, 0);   // A-kc0(0), B-kc0(0)
  STG(0, 1, 0, 0); STG(1, 1, 0, 0);   // A-kc1(0), B-kc1(0)
  STG(0, 0, 1, 1); STG(1, 0, 1, 1);   // A-kc0(1), B-kc0(1)

  for (int kt = 0; kt < NT; ++kt) {
    const int cur = kt & 1;
    GATE();
    if (kt + 1 < NT) STG(0, 1, kt + 1, cur ^ 1);
    CMP(cur, 0, 0);
    __builtin_amdgcn_s_barrier();
    if (kt + 1 < NT) STG(1, 1, kt + 1, cur ^ 1);
    CMP(cur, 0, 1);
    GATE();
    if (kt + 2 < NT) STG(0, 0, kt + 2, cur);
    CMP(cur, 1, 0);
    __builtin_amdgcn_s_barrier();
    if (kt + 2 < NT) STG(1, 0, kt + 2, cur);
    CMP(cur, 1, 1);
  }
#undef STG
#undef GATE
#undef CMP

#pragma unroll
  for (int fr = 0; fr < 8; ++fr)
#pragma unroll
    for (int fn = 0; fn < 4; ++fn) {
      int rr = rowBase + wm * 128 + fr * 16 + l4 * 4;
      int cc = colBase + wn * 64 + fn * 16 + m16;
#pragma unroll
      for (int jr = 0; jr < 4; ++jr) {
        if (BF16OUT)
          ((unsigned short*)Cv)[(size_t)(rr + jr) * N + cc] = f2bf(acc[fr][fn][jr]);
        else
          ((float*)Cv)[(size_t)(rr + jr) * N + cc] = acc[fr][fn][jr];
      }
    }
}

// ---------------- 256x128 8-phase GEMM (f32 out): full-fill variant for out-proj ----------
__global__ __launch_bounds__(512, 2) void gemm256_n128(const unsigned short* __restrict__ A,
                                                       const unsigned short* __restrict__ BT,
                                                       float* __restrict__ Cv,
                                                       int M, int N, int K) {
  __shared__ __align__(16) char Lds[98304];  // per buf: A 2x16KB + B 2x8KB = 48KB
  const int t = threadIdx.x, lane = t & 63;
  const int wid = t >> 6, m16 = lane & 15, l4 = lane >> 4;
  const int wm = wid >> 2, wn = wid & 3;
  const int swA = (l4 ^ ((m16 >> 1) & 3)) * 16;

  int gx = gridDim.x, nwg = gx * gridDim.y;
  int wg = blockIdx.y * gx + blockIdx.x;
  if ((nwg & 7) == 0) { int q = nwg >> 3; wg = (wg & 7) * q + (wg >> 3); }
  const int rowBase = (wg / gx) * 256, colBase = (wg % gx) * 128;

  const int r0 = t >> 2, c80 = (t & 3) ^ ((r0 >> 1) & 3);
  const int g1 = 512 + t, r1 = g1 >> 2, c81 = (g1 & 3) ^ ((r1 >> 1) & 3);
  const char* pA0 = (const char*)(A + (size_t)(rowBase + r0) * K + c80 * 8);
  const char* pA1 = (const char*)(A + (size_t)(rowBase + r1) * K + c81 * 8);
  const char* pB0 = (const char*)(BT + (size_t)(colBase + r0) * K + c80 * 8);

  f32x4 acc[8][2];
#pragma unroll
  for (int fr = 0; fr < 8; ++fr)
#pragma unroll
    for (int fn = 0; fn < 2; ++fn) {
      f32x4 z = {0.f, 0.f, 0.f, 0.f};
      acc[fr][fn] = z;
    }
  s16x8 bf[2];

#define ABASE(buf, kc) (Lds + (buf) * 49152 + (kc) * 16384)
#define BBASE(buf, kc) (Lds + (buf) * 49152 + 32768 + (kc) * 8192)

#define STGA(kc, kt, buf)                                                 \
  {                                                                       \
    size_t ko = (size_t)((kt) * 64 + (kc) * 32) * 2;                      \
    gl_lds16(pA0 + ko, ABASE(buf, kc) + t * 16);                          \
    gl_lds16(pA1 + ko, ABASE(buf, kc) + 8192 + t * 16);                   \
  }
#define STGB(kc, kt, buf)                                                 \
  {                                                                       \
    size_t ko = (size_t)((kt) * 64 + (kc) * 32) * 2;                      \
    gl_lds16(pB0 + ko, BBASE(buf, kc) + t * 16);                          \
  }

#define GATE()                                         \
  asm volatile("s_waitcnt vmcnt(6)" ::: "memory");     \
  __builtin_amdgcn_s_barrier();                        \
  __builtin_amdgcn_sched_barrier(0);

#define CMP(cur, kc, frh)                                                          \
  {                                                                                \
    const char* Ap = ABASE(cur, kc);                                               \
    s16x8 af[4];                                                                   \
    _Pragma("unroll") for (int i = 0; i < 4; ++i)                                  \
        af[i] = *(const s16x8*)(Ap + (wm * 128 + ((frh) * 4 + i) * 16 + m16) * 64 + swA); \
    if ((frh) == 0) {                                                              \
      const char* Bp = BBASE(cur, kc);                                             \
      _Pragma("unroll") for (int n = 0; n < 2; ++n)                                \
          bf[n] = *(const s16x8*)(Bp + (wn * 32 + n * 16 + m16) * 64 + swA);       \
    }                                                                              \
    __builtin_amdgcn_s_setprio(1);                                                 \
    _Pragma("unroll") for (int i = 0; i < 4; ++i)                                  \
        _Pragma("unroll") for (int n = 0; n < 2; ++n)                              \
            acc[(frh) * 4 + i][n] = __builtin_amdgcn_mfma_f32_16x16x32_bf16(       \
                af[i], bf[n], acc[(frh) * 4 + i][n], 0, 0, 0);                     \
    __builtin_amdgcn_s_setprio(0);                                                 \
  }

  const int NT = K >> 6;
  STGA(0, 0, 0); STGB(0, 0, 0);
  STGA(1, 0, 0); STGB(1, 0, 0);
  STGA(0, 1, 1); STGB(0, 1, 1);

  for (int kt = 0; kt < NT; ++kt) {
    const int cur = kt & 1;
    GATE();
    if (kt + 1 < NT) STGA(1, kt + 1, cur ^ 1);
    CMP(cur, 0, 0);
    __builtin_amdgcn_s_barrier();
    if (kt + 1 < NT) STGB(1, kt + 1, cur ^ 1);
    CMP(cur, 0, 1);
    GATE();
    if (kt + 2 < NT) STGA(0, kt + 2, cur);
    CMP(cur, 1, 0);
    __builtin_amdgcn_s_barrier();
    if (kt + 2 < NT) STGB(0, kt + 2, cur);
    CMP(cur, 1, 1);
  }
#undef STGA
#undef STGB
#undef GATE
#undef CMP
#undef ABASE
#undef BBASE

#pragma unroll
  for (int fr = 0; fr < 8; ++fr)
#pragma unroll
    for (int fn = 0; fn < 2; ++fn) {
      int rr = rowBase + wm * 128 + fr * 16 + l4 * 4;
      int cc = colBase + wn * 32 + fn * 16 + m16;
#pragma unroll
      for (int jr = 0; jr < 4; ++jr)
        Cv[(size_t)(rr + jr) * N + cc] = acc[fr][fn][jr];
    }
}

// ---------------- flash attention (non-causal, GQA rep=4), 32x32 MFMA, 2 q-sets ----------
// 4 waves x 64 q-rows (2 sets of 32) = 256 q/block; grid 8x16x2 = 256 blocks (1/CU).
// Each K-frag / V-frag LDS read feeds TWO MFMAs (one per q-set): read:MFMA = 0.5.
// In-register P via cvt_pk + permlane32_swap (T12); fixed-m softmax.
__global__ __launch_bounds__(256, 1) void attn_kernel(const unsigned short* __restrict__ qkv,
                                                      const unsigned short* __restrict__ vt,
                                                      unsigned short* __restrict__ obuf) {
  __shared__ __align__(16) unsigned short Kl[2][64 * 128];
  __shared__ __align__(16) unsigned short Vl[2][128 * 64];
  const int t = threadIdx.x, lane = t & 63, w = t >> 6;
  const int q32 = lane & 31, l32 = lane >> 5;
  const int b = blockIdx.z, h = blockIdx.y, qb = blockIdx.x;
  const int kvh = h >> 2;
  const float SCL = 0.12751744616570824f;  // (1/sqrt(128)) * log2(e)

  // Q frags (B-operand of 32x32x16), two q-sets at rows +0 and +32
  s16x8 qf[2][8];
  {
    const unsigned short* qp =
        qkv + (size_t)(b * 2048 + qb * 256 + w * 64 + q32) * 3072 + h * 128 + l32 * 8;
#pragma unroll
    for (int qs = 0; qs < 2; ++qs)
#pragma unroll
      for (int ds = 0; ds < 8; ++ds)
        qf[qs][ds] = *(const s16x8*)(qp + qs * 32 * 3072 + ds * 16);
  }

  float lsum[2];
  f32x16 acco[2][4];
#pragma unroll
  for (int qs = 0; qs < 2; ++qs) {
    lsum[qs] = 0.f;
#pragma unroll
    for (int dt = 0; dt < 4; ++dt) acco[qs][dt] = (f32x16){};
  }

  // per-thread staging pointers: 4 K chunks + 4 V chunks (16B each), source pre-swizzled
  const char* pK[4];
  const char* pV[4];
#pragma unroll
  for (int i = 0; i < 4; ++i) {
    int c = i * 256 + t;
    {
      int row = c >> 4, ch = c & 15;  // K tile: 64 rows x 16 chunks (256B rows)
      pK[i] = (const char*)(qkv + (size_t)(b * 2048 + row) * 3072 + 2048 + kvh * 128) +
              ((ch * 16) ^ ((row & 7) << 4));
    }
    {
      int d = c >> 3, ch = c & 7;     // V tile: 128 d-rows x 8 chunks (128B rows)
      pV[i] = (const char*)(vt + (size_t)((b * 4 + kvh) * 128 + d) * 2048) +
              ((ch * 16) ^ ((d & 7) << 4));
    }
  }
  const size_t KADV = (size_t)64 * 3072 * 2;  // 64 seq rows
  const size_t VADV = 128;                    // 64 k-cols * 2B

#define STAGE_T(buf)                                                         \
  {                                                                          \
    _Pragma("unroll") for (int i = 0; i < 4; ++i)                            \
        gl_lds16(pK[i], (char*)Kl[buf] + (i * 256 + t) * 16);                \
    _Pragma("unroll") for (int i = 0; i < 4; ++i)                            \
        gl_lds16(pV[i], (char*)Vl[buf] + (i * 256 + t) * 16);                \
    _Pragma("unroll") for (int i = 0; i < 4; ++i) pK[i] += KADV;             \
    _Pragma("unroll") for (int i = 0; i < 4; ++i) pV[i] += VADV;             \
  }

  int cur = 0;
  STAGE_T(0);

  for (int kt = 0; kt < 32; ++kt) {
    // ---- top gate: issue next-tile loads, wait for cur's loads, sync ----
    if (kt < 31) {
      STAGE_T(cur ^ 1);
      asm volatile("s_waitcnt vmcnt(8)" ::: "memory");  // cur's 8 loads landed
    } else {
      asm volatile("s_waitcnt vmcnt(0)" ::: "memory");
    }
    __builtin_amdgcn_s_barrier();
    __builtin_amdgcn_sched_barrier(0);

    // ---- S^T = K Q^T (32x32x16): each kf read feeds both q-sets ----
    f32x16 sc32[2][2];
    __builtin_amdgcn_s_setprio(1);
#pragma unroll
    for (int kt32 = 0; kt32 < 2; ++kt32) {
      f32x16 a0 = (f32x16){};
      f32x16 a1 = (f32x16){};
      int r = kt32 * 32 + q32;
      const char* kr = (const char*)Kl[cur] + r * 256;
      int sw = (r & 7) << 4;
#pragma unroll
      for (int ds = 0; ds < 8; ++ds) {
        s16x8 kf = *(const s16x8*)(kr + ((ds * 32 + l32 * 16) ^ sw));
        a0 = __builtin_amdgcn_mfma_f32_32x32x16_bf16(kf, qf[0][ds], a0, 0, 0, 0);
        a1 = __builtin_amdgcn_mfma_f32_32x32x16_bf16(kf, qf[1][ds], a1, 0, 0, 0);
      }
      sc32[0][kt32] = a0;
      sc32[1][kt32] = a1;
    }
    __builtin_amdgcn_s_setprio(0);

    // ---- fixed-m softmax per q-set: e = 2^(S*SCL); cvt_pk; permlane -> B-frags ----
    s16x8 bfrag[2][4];
#pragma unroll
    for (int qs = 0; qs < 2; ++qs) {
      float part = 0.f;
#pragma unroll
      for (int kt32 = 0; kt32 < 2; ++kt32) {
        float e[16];
#pragma unroll
        for (int rg = 0; rg < 16; ++rg) {
          float x = sc32[qs][kt32][rg] * SCL;
          asm("v_exp_f32 %0, %1" : "=v"(e[rg]) : "v"(x));
        }
#pragma unroll
        for (int rg = 0; rg < 16; ++rg) part += e[rg];
        unsigned int pr[4][2];
#pragma unroll
        for (int a2 = 0; a2 < 4; ++a2) {
          asm("v_cvt_pk_bf16_f32 %0, %1, %2"
              : "=v"(pr[a2][0]) : "v"(e[a2 * 4 + 0]), "v"(e[a2 * 4 + 1]));
          asm("v_cvt_pk_bf16_f32 %0, %1, %2"
              : "=v"(pr[a2][1]) : "v"(e[a2 * 4 + 2]), "v"(e[a2 * 4 + 3]));
        }
#pragma unroll
        for (int hf = 0; hf < 2; ++hf) {
          unsigned int x0 = pr[2 * hf][0], y0 = pr[2 * hf + 1][0];
          unsigned int x1 = pr[2 * hf][1], y1 = pr[2 * hf + 1][1];
          asm("v_permlane32_swap_b32 %0, %1" : "+v"(x0), "+v"(y0));
          asm("v_permlane32_swap_b32 %0, %1" : "+v"(x1), "+v"(y1));
          union { unsigned int u[4]; s16x8 v; } bb;
          bb.u[0] = x0; bb.u[1] = x1; bb.u[2] = y0; bb.u[3] = y1;
          bfrag[qs][kt32 * 2 + hf] = bb.v;
        }
      }
      lsum[qs] += part;
    }

    // ---- O^T += V^T P^T (32x32x16): each vf read feeds both q-sets ----
    __builtin_amdgcn_s_setprio(1);
#pragma unroll
    for (int dt = 0; dt < 4; ++dt) {
      int d = dt * 32 + q32;
      const char* vr = (const char*)Vl[cur] + d * 128;
      int swv = (d & 7) << 4;
#pragma unroll
      for (int ts = 0; ts < 4; ++ts) {
        s16x8 vf = *(const s16x8*)(vr + ((ts * 32 + l32 * 16) ^ swv));
        acco[0][dt] = __builtin_amdgcn_mfma_f32_32x32x16_bf16(vf, bfrag[0][ts], acco[0][dt], 0, 0, 0);
        acco[1][dt] = __builtin_amdgcn_mfma_f32_32x32x16_bf16(vf, bfrag[1][ts], acco[1][dt], 0, 0, 0);
      }
    }
    __builtin_amdgcn_s_setprio(0);
    // ---- end barrier: all reads of cur done before next iter stages into cur ----
    __builtin_amdgcn_s_barrier();
    cur ^= 1;
  }
#undef STAGE_T

  // ---- finalize per q-set: lanes l and l+32 hold complementary k-halves ----
#pragma unroll
  for (int qs = 0; qs < 2; ++qs) {
    float s = lsum[qs];
    s += __shfl_xor(s, 32);
    float iv = 1.0f / s;
    unsigned short* op =
        obuf + (size_t)(b * 2048 + qb * 256 + w * 64 + qs * 32 + q32) * 2048 + h * 128;
#pragma unroll
    for (int dt = 0; dt < 4; ++dt)
#pragma unroll
      for (int rg = 0; rg < 16; ++rg) {
        int d = dt * 32 + (rg & 3) + 8 * (rg >> 2) + 4 * l32;
        op[d] = f2bf(acco[qs][dt][rg] * iv);
      }
  }
}

extern "C" void kernel_launch(void* const* d_in, const int* in_sizes, int n_in,
                              void* d_out, int out_size, void* d_ws, size_t ws_size,
                              hipStream_t stream) {
  (void)in_sizes; (void)n_in; (void)out_size; (void)ws_size;
  const float* x  = (const float*)d_in[0];
  const float* wq = (const float*)d_in[1];
  const float* wk = (const float*)d_in[2];
  const float* wv = (const float*)d_in[3];
  const float* wo = (const float*)d_in[4];

  char* ws = (char*)d_ws;
  unsigned short* xb    = (unsigned short*)(ws);              // 4096x2048 bf16 (16.78 MB)
  unsigned short* wqkvT = (unsigned short*)(ws + 16777216);   // 3072x2048 bf16 (12.58 MB)
  unsigned short* woT   = (unsigned short*)(ws + 29360128);   // 2048x2048 bf16 (8.39 MB)
  unsigned short* qkv   = (unsigned short*)(ws + 37748736);   // 4096x3072 bf16 (25.17 MB)
  unsigned short* obuf  = (unsigned short*)(ws + 62914560);   // 4096x2048 bf16 (16.78 MB)
  float* ct             = (float*)(ws + 79691776);            // 2048x64 f32
  float* st             = (float*)(ws + 80216064);            // 2048x64 f32
  unsigned short* vt    = xb;  // aliases xb: xb is dead after the QKV GEMM (8.39 MB used)

  cast_to_bf16<<<8192, 256, 0, stream>>>(x, xb, 2097152);
  transpose_cast<<<dim3(64, 64), 256, 0, stream>>>(wq, wqkvT, 2048, 2048);
  transpose_cast<<<dim3(16, 64), 256, 0, stream>>>(wk, wqkvT + 2048 * 2048, 2048, 512);
  transpose_cast<<<dim3(16, 64), 256, 0, stream>>>(wv, wqkvT + 2560 * 2048, 2048, 512);
  transpose_cast<<<dim3(64, 64), 256, 0, stream>>>(wo, woT, 2048, 2048);
  rope_tables<<<512, 256, 0, stream>>>(ct, st);
  gemm256<1><<<dim3(12, 16), 512, 0, stream>>>(xb, wqkvT, qkv, 4096, 3072, 2048);
  rope_apply<<<4096, 256, 0, stream>>>(qkv, ct, st);
  vtrans<<<dim3(64, 4, 8), 256, 0, stream>>>(qkv, vt);
  attn_kernel<<<dim3(8, 16, 2), 256, 0, stream>>>(qkv, vt, obuf);
  gemm256_n128<<<dim3(16, 16), 512, 0, stream>>>(obuf, woT, (float*)d_out, 4096, 2048, 2048);
}

// Round 14
// 211.152 us; speedup vs baseline: 1.0910x; 1.0910x over previous
//
#include <hip/hip_runtime.h>
#include <hip/hip_bf16.h>

typedef __attribute__((ext_vector_type(8))) short s16x8;
typedef __attribute__((ext_vector_type(4))) float f32x4;
typedef __attribute__((ext_vector_type(16))) float f32x16;

__device__ inline float bf2f(unsigned short u) {
  union { unsigned int i; float f; } v; v.i = ((unsigned int)u) << 16; return v.f;
}
__device__ inline unsigned short f2bf(float f) {
  union { float f; unsigned int i; } v; v.f = f;
  unsigned int r = (v.i + 0x7FFFu + ((v.i >> 16) & 1u)) >> 16;
  return (unsigned short)r;
}
__device__ inline void gl_lds16(const void* g, void* l) {
  __builtin_amdgcn_global_load_lds(
      (const __attribute__((address_space(1))) unsigned int*)g,
      (__attribute__((address_space(3))) unsigned int*)l, 16, 0, 0);
}

// ---------------- elementwise cast x -> bf16 ----------------
__global__ __launch_bounds__(256) void cast_to_bf16(const float* __restrict__ s,
                                                    unsigned short* __restrict__ d, int n4) {
  int i = blockIdx.x * 256 + threadIdx.x;
  if (i >= n4) return;
  float4 v = ((const float4*)s)[i];
  ushort4 o;
  o.x = f2bf(v.x); o.y = f2bf(v.y); o.z = f2bf(v.z); o.w = f2bf(v.w);
  ((ushort4*)d)[i] = o;
}

// ---- merged transpose+cast for wq|wk|wv -> wqkvT[N:3072][K:2048] (one launch) ----
// bx in [0,64): wq (N=2048, dst rows 0..2047); [64,80): wk (dst rows 2048..2559);
// [80,96): wv (dst rows 2560..3071). Identical 32x32 tile math as before.
__global__ __launch_bounds__(256) void transpose_cast_qkvw(const float* __restrict__ wq,
                                                           const float* __restrict__ wk,
                                                           const float* __restrict__ wv,
                                                           unsigned short* __restrict__ dst) {
  __shared__ float tile[32][33];
  int bx = blockIdx.x;
  const float* src;
  int N, n0, rowoff;
  if (bx < 64)      { src = wq; N = 2048; n0 = bx * 32;        rowoff = 0;    }
  else if (bx < 80) { src = wk; N = 512;  n0 = (bx - 64) * 32; rowoff = 2048; }
  else              { src = wv; N = 512;  n0 = (bx - 80) * 32; rowoff = 2560; }
  int k0 = blockIdx.y * 32;
  int tx = threadIdx.x & 31, ty = threadIdx.x >> 5;
#pragma unroll
  for (int i = 0; i < 4; ++i) {
    int k = ty + i * 8;
    tile[k][tx] = src[(size_t)(k0 + k) * N + n0 + tx];
  }
  __syncthreads();
#pragma unroll
  for (int i = 0; i < 4; ++i) {
    int n = ty + i * 8;
    dst[(size_t)(rowoff + n0 + n) * 2048 + k0 + tx] = f2bf(tile[tx][n]);
  }
}

// ---------------- transpose + cast weight: src[K][N] f32 -> dst[N][K] bf16 ----------------
__global__ __launch_bounds__(256) void transpose_cast(const float* __restrict__ src,
                                                      unsigned short* __restrict__ dst,
                                                      int K, int N) {
  __shared__ float tile[32][33];
  int n0 = blockIdx.x * 32, k0 = blockIdx.y * 32;
  int tx = threadIdx.x & 31, ty = threadIdx.x >> 5;
#pragma unroll
  for (int i = 0; i < 4; ++i) {
    int k = ty + i * 8;
    tile[k][tx] = src[(size_t)(k0 + k) * N + n0 + tx];
  }
  __syncthreads();
#pragma unroll
  for (int i = 0; i < 4; ++i) {
    int n = ty + i * 8;
    dst[(size_t)(n0 + n) * K + k0 + tx] = f2bf(tile[tx][n]);
  }
}

// ---------------- RoPE tables ----------------
__global__ __launch_bounds__(256) void rope_tables(float* __restrict__ ct, float* __restrict__ st) {
  int idx = blockIdx.x * 256 + threadIdx.x;  // 2048*64
  int s = idx >> 6, i = idx & 63;
  float inv = powf(10000.0f, -(float)(2 * i) * (1.0f / 128.0f));
  float ang = (float)s * inv;
  ct[idx] = cosf(ang);
  st[idx] = sinf(ang);
}

// ---------------- RoPE apply in place on Q (16 heads) and K (4 heads) ----------------
__global__ __launch_bounds__(256) void rope_apply(unsigned short* __restrict__ qkv,
                                                  const float* __restrict__ ct,
                                                  const float* __restrict__ st) {
  int row = blockIdx.x;  // 0..4095 = b*2048+s
  int pos = row & 2047;
  unsigned short* base = qkv + (size_t)row * 3072;
  for (int it = threadIdx.x; it < 1280; it += 256) {  // 20 heads * 64 half-dims
    int head = it >> 6, dh = it & 63;
    int col = head < 16 ? head * 128 : 2048 + (head - 16) * 128;
    float a = bf2f(base[col + dh]);
    float b = bf2f(base[col + dh + 64]);
    float c = ct[pos * 64 + dh], sn = st[pos * 64 + dh];
    base[col + dh] = f2bf(a * c - b * sn);
    base[col + dh + 64] = f2bf(b * c + a * sn);
  }
}

// ---------------- V transpose: qkv V cols -> vt[(b*4+kvh)*128 + d][s] ----------------
__global__ __launch_bounds__(256) void vtrans(const unsigned short* __restrict__ qkv,
                                              unsigned short* __restrict__ vt) {
  __shared__ unsigned short tile[32][33];
  int tx = threadIdx.x & 31, ty = threadIdx.x >> 5;
  int s0 = blockIdx.x * 32;
  int d0 = blockIdx.y * 32;
  int bz = blockIdx.z;  // b*4 + kvh
  const unsigned short* src = qkv + (size_t)((bz >> 2) * 2048) * 3072 + 2560 + (bz & 3) * 128;
#pragma unroll
  for (int i = 0; i < 4; ++i)
    tile[ty + i * 8][tx] = src[(size_t)(s0 + ty + i * 8) * 3072 + d0 + tx];
  __syncthreads();
  unsigned short* dst = vt + (size_t)bz * 128 * 2048;
#pragma unroll
  for (int i = 0; i < 4; ++i)
    dst[(size_t)(d0 + ty + i * 8) * 2048 + s0 + tx] = tile[tx][ty + i * 8];
}

// ---------------- 256x256 8-phase GEMM: C[M,N] = A[M,K] * BT[N,K]^T ----------------
template <int BF16OUT>
__global__ __launch_bounds__(512, 2) void gemm256(const unsigned short* __restrict__ A,
                                                  const unsigned short* __restrict__ BT,
                                                  void* __restrict__ Cv,
                                                  int M, int N, int K) {
  __shared__ __align__(16) unsigned short Lds[2][4][256 * 32];  // 128 KiB
  const int t = threadIdx.x, lane = t & 63;
  const int wid = t >> 6, m16 = lane & 15, l4 = lane >> 4;
  const int wm = wid >> 2, wn = wid & 3;
  const int swA = (l4 ^ ((m16 >> 1) & 3)) * 16;  // read-side swizzled 16B slot

  int gx = gridDim.x, nwg = gx * gridDim.y;
  int wg = blockIdx.y * gx + blockIdx.x;
  if ((nwg & 7) == 0) { int q = nwg >> 3; wg = (wg & 7) * q + (wg >> 3); }
  const int rowBase = (wg / gx) * 256, colBase = (wg % gx) * 256;

  const int r0 = t >> 2, c80 = (t & 3) ^ ((r0 >> 1) & 3);
  const int g1 = 512 + t, r1 = g1 >> 2, c81 = (g1 & 3) ^ ((r1 >> 1) & 3);
  const char* pA0 = (const char*)(A + (size_t)(rowBase + r0) * K + c80 * 8);
  const char* pA1 = (const char*)(A + (size_t)(rowBase + r1) * K + c81 * 8);
  const char* pB0 = (const char*)(BT + (size_t)(colBase + r0) * K + c80 * 8);
  const char* pB1 = (const char*)(BT + (size_t)(colBase + r1) * K + c81 * 8);

  f32x4 acc[8][4];
#pragma unroll
  for (int fr = 0; fr < 8; ++fr)
#pragma unroll
    for (int fn = 0; fn < 4; ++fn) {
      f32x4 z = {0.f, 0.f, 0.f, 0.f};
      acc[fr][fn] = z;
    }
  s16x8 bf[4];

#define STG(mat, kc, kt, buf)                                             \
  {                                                                       \
    size_t ko = (size_t)((kt) * 64 + (kc) * 32) * 2;                      \
    char* pl = (char*)&Lds[buf][(mat) * 2 + (kc)][0];                     \
    gl_lds16(((mat) ? pB0 : pA0) + ko, pl + t * 16);                      \
    gl_lds16(((mat) ? pB1 : pA1) + ko, pl + 8192 + t * 16);               \
  }

#define GATE()                                         \
  asm volatile("s_waitcnt vmcnt(8)" ::: "memory");     \
  __builtin_amdgcn_s_barrier();                        \
  __builtin_amdgcn_sched_barrier(0);

#define CMP(cur, kc, frh)                                                          \
  {                                                                                \
    const char* Ap = (const char*)&Lds[cur][kc][0];                                \
    s16x8 af[4];                                                                   \
    _Pragma("unroll") for (int i = 0; i < 4; ++i)                                  \
        af[i] = *(const s16x8*)(Ap + (wm * 128 + ((frh) * 4 + i) * 16 + m16) * 64 + swA); \
    if ((frh) == 0) {                                                              \
      const char* Bp = (const char*)&Lds[cur][2 + (kc)][0];                        \
      _Pragma("unroll") for (int n = 0; n < 4; ++n)                                \
          bf[n] = *(const s16x8*)(Bp + (wn * 64 + n * 16 + m16) * 64 + swA);       \
    }                                                                              \
    __builtin_amdgcn_s_setprio(1);                                                 \
    _Pragma("unroll") for (int i = 0; i < 4; ++i)                                  \
        _Pragma("unroll") for (int n = 0; n < 4; ++n)                              \
            acc[(frh) * 4 + i][n] = __builtin_amdgcn_mfma_f32_16x16x32_bf16(       \
                af[i], bf[n], acc[(frh) * 4 + i][n], 0, 0, 0);                     \
    __builtin_amdgcn_s_setprio(0);                                                 \
  }

  const int NT = K >> 6;
  STG(0, 0, 0, 0); STG(1, 0, 0, 0);   // A-kc0(0), B-kc0(0)
  STG(0, 1, 0, 0); STG(1, 1, 0, 0);   // A-kc1(0), B-kc1(0)
  STG(0, 0, 1, 1); STG(1, 0, 1, 1);   // A-kc0(1), B-kc0(1)

  for (int kt = 0; kt < NT; ++kt) {
    const int cur = kt & 1;
    GATE();
    if (kt + 1 < NT) STG(0, 1, kt + 1, cur ^ 1);
    CMP(cur, 0, 0);
    __builtin_amdgcn_s_barrier();
    if (kt + 1 < NT) STG(1, 1, kt + 1, cur ^ 1);
    CMP(cur, 0, 1);
    GATE();
    if (kt + 2 < NT) STG(0, 0, kt + 2, cur);
    CMP(cur, 1, 0);
    __builtin_amdgcn_s_barrier();
    if (kt + 2 < NT) STG(1, 0, kt + 2, cur);
    CMP(cur, 1, 1);
  }
#undef STG
#undef GATE
#undef CMP

#pragma unroll
  for (int fr = 0; fr < 8; ++fr)
#pragma unroll
    for (int fn = 0; fn < 4; ++fn) {
      int rr = rowBase + wm * 128 + fr * 16 + l4 * 4;
      int cc = colBase + wn * 64 + fn * 16 + m16;
#pragma unroll
      for (int jr = 0; jr < 4; ++jr) {
        if (BF16OUT)
          ((unsigned short*)Cv)[(size_t)(rr + jr) * N + cc] = f2bf(acc[fr][fn][jr]);
        else
          ((float*)Cv)[(size_t)(rr + jr) * N + cc] = acc[fr][fn][jr];
      }
    }
}

// ---------------- 256x128 8-phase GEMM (f32 out): full-fill variant for out-proj ----------
__global__ __launch_bounds__(512, 2) void gemm256_n128(const unsigned short* __restrict__ A,
                                                       const unsigned short* __restrict__ BT,
                                                       float* __restrict__ Cv,
                                                       int M, int N, int K) {
  __shared__ __align__(16) char Lds[98304];  // per buf: A 2x16KB + B 2x8KB = 48KB
  const int t = threadIdx.x, lane = t & 63;
  const int wid = t >> 6, m16 = lane & 15, l4 = lane >> 4;
  const int wm = wid >> 2, wn = wid & 3;
  const int swA = (l4 ^ ((m16 >> 1) & 3)) * 16;

  int gx = gridDim.x, nwg = gx * gridDim.y;
  int wg = blockIdx.y * gx + blockIdx.x;
  if ((nwg & 7) == 0) { int q = nwg >> 3; wg = (wg & 7) * q + (wg >> 3); }
  const int rowBase = (wg / gx) * 256, colBase = (wg % gx) * 128;

  const int r0 = t >> 2, c80 = (t & 3) ^ ((r0 >> 1) & 3);
  const int g1 = 512 + t, r1 = g1 >> 2, c81 = (g1 & 3) ^ ((r1 >> 1) & 3);
  const char* pA0 = (const char*)(A + (size_t)(rowBase + r0) * K + c80 * 8);
  const char* pA1 = (const char*)(A + (size_t)(rowBase + r1) * K + c81 * 8);
  const char* pB0 = (const char*)(BT + (size_t)(colBase + r0) * K + c80 * 8);

  f32x4 acc[8][2];
#pragma unroll
  for (int fr = 0; fr < 8; ++fr)
#pragma unroll
    for (int fn = 0; fn < 2; ++fn) {
      f32x4 z = {0.f, 0.f, 0.f, 0.f};
      acc[fr][fn] = z;
    }
  s16x8 bf[2];

#define ABASE(buf, kc) (Lds + (buf) * 49152 + (kc) * 16384)
#define BBASE(buf, kc) (Lds + (buf) * 49152 + 32768 + (kc) * 8192)

#define STGA(kc, kt, buf)                                                 \
  {                                                                       \
    size_t ko = (size_t)((kt) * 64 + (kc) * 32) * 2;                      \
    gl_lds16(pA0 + ko, ABASE(buf, kc) + t * 16);                          \
    gl_lds16(pA1 + ko, ABASE(buf, kc) + 8192 + t * 16);                   \
  }
#define STGB(kc, kt, buf)                                                 \
  {                                                                       \
    size_t ko = (size_t)((kt) * 64 + (kc) * 32) * 2;                      \
    gl_lds16(pB0 + ko, BBASE(buf, kc) + t * 16);                          \
  }

#define GATE()                                         \
  asm volatile("s_waitcnt vmcnt(6)" ::: "memory");     \
  __builtin_amdgcn_s_barrier();                        \
  __builtin_amdgcn_sched_barrier(0);

#define CMP(cur, kc, frh)                                                          \
  {                                                                                \
    const char* Ap = ABASE(cur, kc);                                               \
    s16x8 af[4];                                                                   \
    _Pragma("unroll") for (int i = 0; i < 4; ++i)                                  \
        af[i] = *(const s16x8*)(Ap + (wm * 128 + ((frh) * 4 + i) * 16 + m16) * 64 + swA); \
    if ((frh) == 0) {                                                              \
      const char* Bp = BBASE(cur, kc);                                             \
      _Pragma("unroll") for (int n = 0; n < 2; ++n)                                \
          bf[n] = *(const s16x8*)(Bp + (wn * 32 + n * 16 + m16) * 64 + swA);       \
    }                                                                              \
    __builtin_amdgcn_s_setprio(1);                                                 \
    _Pragma("unroll") for (int i = 0; i < 4; ++i)                                  \
        _Pragma("unroll") for (int n = 0; n < 2; ++n)                              \
            acc[(frh) * 4 + i][n] = __builtin_amdgcn_mfma_f32_16x16x32_bf16(       \
                af[i], bf[n], acc[(frh) * 4 + i][n], 0, 0, 0);                     \
    __builtin_amdgcn_s_setprio(0);                                                 \
  }

  const int NT = K >> 6;
  STGA(0, 0, 0); STGB(0, 0, 0);
  STGA(1, 0, 0); STGB(1, 0, 0);
  STGA(0, 1, 1); STGB(0, 1, 1);

  for (int kt = 0; kt < NT; ++kt) {
    const int cur = kt & 1;
    GATE();
    if (kt + 1 < NT) STGA(1, kt + 1, cur ^ 1);
    CMP(cur, 0, 0);
    __builtin_amdgcn_s_barrier();
    if (kt + 1 < NT) STGB(1, kt + 1, cur ^ 1);
    CMP(cur, 0, 1);
    GATE();
    if (kt + 2 < NT) STGA(0, kt + 2, cur);
    CMP(cur, 1, 0);
    __builtin_amdgcn_s_barrier();
    if (kt + 2 < NT) STGB(0, kt + 2, cur);
    CMP(cur, 1, 1);
  }
#undef STGA
#undef STGB
#undef GATE
#undef CMP
#undef ABASE
#undef BBASE

#pragma unroll
  for (int fr = 0; fr < 8; ++fr)
#pragma unroll
    for (int fn = 0; fn < 2; ++fn) {
      int rr = rowBase + wm * 128 + fr * 16 + l4 * 4;
      int cc = colBase + wn * 32 + fn * 16 + m16;
#pragma unroll
      for (int jr = 0; jr < 4; ++jr)
        Cv[(size_t)(rr + jr) * N + cc] = acc[fr][fn][jr];
    }
}

// ---------------- flash attention (non-causal, GQA rep=4), 32x32 MFMA + in-reg P ----------
// (round-12 kernel, byte-identical: best measured 83.5 us; LDS-BW-saturated per model)
__global__ __launch_bounds__(256, 2) void attn_kernel(const unsigned short* __restrict__ qkv,
                                                      const unsigned short* __restrict__ vt,
                                                      unsigned short* __restrict__ obuf) {
  __shared__ __align__(16) unsigned short Kl[2][64 * 128];
  __shared__ __align__(16) unsigned short Vl[2][128 * 64];
  const int t = threadIdx.x, lane = t & 63, w = t >> 6;
  const int q32 = lane & 31, l32 = lane >> 5;
  const int b = blockIdx.z, h = blockIdx.y, qb = blockIdx.x;
  const int kvh = h >> 2;
  const float SCL = 0.12751744616570824f;  // (1/sqrt(128)) * log2(e)

  // Q frags (B-operand of 32x32x16): lane holds Q[q=q32][d = ds*16 + l32*8 + j]
  s16x8 qf[8];
  {
    const unsigned short* qp =
        qkv + (size_t)(b * 2048 + qb * 128 + w * 32 + q32) * 3072 + h * 128 + l32 * 8;
#pragma unroll
    for (int ds = 0; ds < 8; ++ds) qf[ds] = *(const s16x8*)(qp + ds * 16);
  }

  float lsum = 0.f;
  f32x16 acco[4];
#pragma unroll
  for (int dt = 0; dt < 4; ++dt) acco[dt] = (f32x16){};

  // per-thread staging pointers: 4 K chunks + 4 V chunks (16B each), source pre-swizzled
  const char* pK[4];
  const char* pV[4];
#pragma unroll
  for (int i = 0; i < 4; ++i) {
    int c = i * 256 + t;
    {
      int row = c >> 4, ch = c & 15;  // K tile: 64 rows x 16 chunks (256B rows)
      pK[i] = (const char*)(qkv + (size_t)(b * 2048 + row) * 3072 + 2048 + kvh * 128) +
              ((ch * 16) ^ ((row & 7) << 4));
    }
    {
      int d = c >> 3, ch = c & 7;     // V tile: 128 d-rows x 8 chunks (128B rows)
      pV[i] = (const char*)(vt + (size_t)((b * 4 + kvh) * 128 + d) * 2048) +
              ((ch * 16) ^ ((d & 7) << 4));
    }
  }
  const size_t KADV = (size_t)64 * 3072 * 2;  // 64 seq rows
  const size_t VADV = 128;                    // 64 k-cols * 2B

#define STAGE_T(buf)                                                         \
  {                                                                          \
    _Pragma("unroll") for (int i = 0; i < 4; ++i)                            \
        gl_lds16(pK[i], (char*)Kl[buf] + (i * 256 + t) * 16);                \
    _Pragma("unroll") for (int i = 0; i < 4; ++i)                            \
        gl_lds16(pV[i], (char*)Vl[buf] + (i * 256 + t) * 16);                \
    _Pragma("unroll") for (int i = 0; i < 4; ++i) pK[i] += KADV;             \
    _Pragma("unroll") for (int i = 0; i < 4; ++i) pV[i] += VADV;             \
  }

  int cur = 0;
  STAGE_T(0);

  for (int kt = 0; kt < 32; ++kt) {
    // ---- top gate: issue next-tile loads, wait for cur's loads, sync ----
    if (kt < 31) {
      STAGE_T(cur ^ 1);
      asm volatile("s_waitcnt vmcnt(8)" ::: "memory");  // cur's 8 loads landed
    } else {
      asm volatile("s_waitcnt vmcnt(0)" ::: "memory");
    }
    __builtin_amdgcn_s_barrier();
    __builtin_amdgcn_sched_barrier(0);

    // ---- S^T = K Q^T (32x32x16): per kt32, accumulate over 8 d-steps ----
    f32x16 sc32[2];
    __builtin_amdgcn_s_setprio(1);
#pragma unroll
    for (int kt32 = 0; kt32 < 2; ++kt32) {
      f32x16 a = (f32x16){};
      int r = kt32 * 32 + q32;
      const char* kr = (const char*)Kl[cur] + r * 256;
      int sw = (r & 7) << 4;
#pragma unroll
      for (int ds = 0; ds < 8; ++ds) {
        s16x8 kf = *(const s16x8*)(kr + ((ds * 32 + l32 * 16) ^ sw));
        a = __builtin_amdgcn_mfma_f32_32x32x16_bf16(kf, qf[ds], a, 0, 0, 0);
      }
      sc32[kt32] = a;
    }
    __builtin_amdgcn_s_setprio(0);

    // ---- fixed-m softmax: e = 2^(S*SCL); pack to bf16 pairs; permlane-swap to B-frags ----
    s16x8 bfrag[4];
    float part = 0.f;
#pragma unroll
    for (int kt32 = 0; kt32 < 2; ++kt32) {
      float e[16];
#pragma unroll
      for (int rg = 0; rg < 16; ++rg) {
        float x = sc32[kt32][rg] * SCL;
        asm("v_exp_f32 %0, %1" : "=v"(e[rg]) : "v"(x));
      }
#pragma unroll
      for (int rg = 0; rg < 16; ++rg) part += e[rg];
      unsigned int pr[4][2];
#pragma unroll
      for (int a2 = 0; a2 < 4; ++a2) {
        asm("v_cvt_pk_bf16_f32 %0, %1, %2"
            : "=v"(pr[a2][0]) : "v"(e[a2 * 4 + 0]), "v"(e[a2 * 4 + 1]));
        asm("v_cvt_pk_bf16_f32 %0, %1, %2"
            : "=v"(pr[a2][1]) : "v"(e[a2 * 4 + 2]), "v"(e[a2 * 4 + 3]));
      }
#pragma unroll
      for (int hf = 0; hf < 2; ++hf) {
        unsigned int x0 = pr[2 * hf][0], y0 = pr[2 * hf + 1][0];
        unsigned int x1 = pr[2 * hf][1], y1 = pr[2 * hf + 1][1];
        asm("v_permlane32_swap_b32 %0, %1" : "+v"(x0), "+v"(y0));
        asm("v_permlane32_swap_b32 %0, %1" : "+v"(x1), "+v"(y1));
        union { unsigned int u[4]; s16x8 v; } bb;
        bb.u[0] = x0; bb.u[1] = x1; bb.u[2] = y0; bb.u[3] = y1;
        bfrag[kt32 * 2 + hf] = bb.v;
      }
    }
    lsum += part;

    // ---- O^T += V^T P^T (32x32x16): 4 d-tiles x 4 k-steps ----
    __builtin_amdgcn_s_setprio(1);
#pragma unroll
    for (int dt = 0; dt < 4; ++dt) {
      int d = dt * 32 + q32;
      const char* vr = (const char*)Vl[cur] + d * 128;
      int swv = (d & 7) << 4;
#pragma unroll
      for (int ts = 0; ts < 4; ++ts) {
        s16x8 vf = *(const s16x8*)(vr + ((ts * 32 + l32 * 16) ^ swv));
        acco[dt] = __builtin_amdgcn_mfma_f32_32x32x16_bf16(vf, bfrag[ts], acco[dt], 0, 0, 0);
      }
    }
    __builtin_amdgcn_s_setprio(0);
    // ---- end barrier: all reads of cur done before next iter stages into cur ----
    __builtin_amdgcn_s_barrier();
    cur ^= 1;
  }
#undef STAGE_T

  // ---- finalize: lanes l and l+32 hold complementary k-halves of the same q ----
  {
    float s = lsum;
    s += __shfl_xor(s, 32);
    float iv = 1.0f / s;
    unsigned short* op =
        obuf + (size_t)(b * 2048 + qb * 128 + w * 32 + q32) * 2048 + h * 128;
#pragma unroll
    for (int dt = 0; dt < 4; ++dt)
#pragma unroll
      for (int rg = 0; rg < 16; ++rg) {
        int d = dt * 32 + (rg & 3) + 8 * (rg >> 2) + 4 * l32;
        op[d] = f2bf(acco[dt][rg] * iv);
      }
  }
}

extern "C" void kernel_launch(void* const* d_in, const int* in_sizes, int n_in,
                              void* d_out, int out_size, void* d_ws, size_t ws_size,
                              hipStream_t stream) {
  (void)in_sizes; (void)n_in; (void)out_size; (void)ws_size;
  const float* x  = (const float*)d_in[0];
  const float* wq = (const float*)d_in[1];
  const float* wk = (const float*)d_in[2];
  const float* wv = (const float*)d_in[3];
  const float* wo = (const float*)d_in[4];

  char* ws = (char*)d_ws;
  unsigned short* xb    = (unsigned short*)(ws);              // 4096x2048 bf16 (16.78 MB)
  unsigned short* wqkvT = (unsigned short*)(ws + 16777216);   // 3072x2048 bf16 (12.58 MB)
  unsigned short* woT   = (unsigned short*)(ws + 29360128);   // 2048x2048 bf16 (8.39 MB)
  unsigned short* qkv   = (unsigned short*)(ws + 37748736);   // 4096x3072 bf16 (25.17 MB)
  unsigned short* obuf  = (unsigned short*)(ws + 62914560);   // 4096x2048 bf16 (16.78 MB)
  float* ct             = (float*)(ws + 79691776);            // 2048x64 f32
  float* st             = (float*)(ws + 80216064);            // 2048x64 f32
  unsigned short* vt    = xb;  // aliases xb: xb is dead after the QKV GEMM (8.39 MB used)

  cast_to_bf16<<<8192, 256, 0, stream>>>(x, xb, 2097152);
  transpose_cast_qkvw<<<dim3(96, 64), 256, 0, stream>>>(wq, wk, wv, wqkvT);
  transpose_cast<<<dim3(64, 64), 256, 0, stream>>>(wo, woT, 2048, 2048);
  rope_tables<<<512, 256, 0, stream>>>(ct, st);
  gemm256<1><<<dim3(12, 16), 512, 0, stream>>>(xb, wqkvT, qkv, 4096, 3072, 2048);
  rope_apply<<<4096, 256, 0, stream>>>(qkv, ct, st);
  vtrans<<<dim3(64, 4, 8), 256, 0, stream>>>(qkv, vt);
  attn_kernel<<<dim3(16, 16, 2), 256, 0, stream>>>(qkv, vt, obuf);
  gemm256_n128<<<dim3(16, 16), 512, 0, stream>>>(obuf, woT, (float*)d_out, 4096, 2048, 2048);
}